// Round 7
// baseline (1541.380 us; speedup 1.0000x reference)
//
#include <hip/hip_runtime.h>

#define DEVFN __device__ __forceinline__

typedef unsigned short ushort_t;
typedef unsigned int uint32;
typedef __attribute__((ext_vector_type(8))) short bf16x8;
typedef __attribute__((ext_vector_type(4))) float f32x4;

typedef __attribute__((address_space(3))) unsigned int lds_uint;
typedef const __attribute__((address_space(1))) unsigned int glob_uint;

DEVFN ushort_t f2bf(float x) {
    uint32 b = __float_as_uint(x);
    uint32 r = (b + 0x7FFFu + ((b >> 16) & 1u)) >> 16;
    return (ushort_t)r;
}
DEVFN float bf2f(ushort_t u) { return __uint_as_float(((uint32)u) << 16); }

union BWU { uint32 u[4]; bf16x8 v8; };

// ---------------------------------------------------------------- prep: wAf (coalesced) + wA2f + x transpose
__global__ __launch_bounds__(256) void k_prep(const float* __restrict__ m1_w,
                                              const float* __restrict__ mt_w,
                                              const float* __restrict__ x,
                                              ushort_t* __restrict__ wAf,
                                              ushort_t* __restrict__ wA2f,
                                              float* __restrict__ xt) {
    const int bid = blockIdx.x, tid = threadIdx.x;
    if (bid < 256) {
        const int p = bid * 4 + (tid >> 6);
        const int lane = tid & 63, l15 = lane & 15, lg = lane >> 4;
        const int cot = p >> 6, cis = p & 63;
        const int co = cot * 16 + l15, k0 = cis * 32 + lg * 8;
        const float* src = m1_w + ((size_t)co * 2048 + k0) * 9;
        float v[72];
#pragma unroll
        for (int i = 0; i < 72; ++i) v[i] = src[i];
#pragma unroll
        for (int tap = 0; tap < 9; ++tap) {
            ushort_t* dst = wAf + ((size_t)((tap * 16 + cot) * 64 + cis) * 512) + lane * 8;
            ushort_t t8[8];
#pragma unroll
            for (int j = 0; j < 8; ++j) t8[j] = f2bf(v[j * 9 + tap]);
            uint4 u;
            u.x = (uint32)t8[0] | ((uint32)t8[1] << 16);
            u.y = (uint32)t8[2] | ((uint32)t8[3] << 16);
            u.z = (uint32)t8[4] | ((uint32)t8[5] << 16);
            u.w = (uint32)t8[6] | ((uint32)t8[7] << 16);
            *(uint4*)dst = u;
        }
    } else if (bid < 1280) {
        int idx = (bid - 256) * 256 + tid;
        int j = idx & 7, lane = (idx >> 3) & 63, cis = (idx >> 9) & 7, cot = idx >> 12;
        int row = cot * 16 + (lane & 15);
        int c = cis * 32 + (lane >> 4) * 8 + j;
        int o = row >> 2, ij = row & 3;
        wA2f[idx] = f2bf(mt_w[((size_t)c * 256 + o) * 4 + ij]);
    } else {
        int pos = bid - 1280;
        for (int i = 0; i < 8; ++i) {
            int c = tid + i * 256;
            xt[(size_t)pos * 2048 + c] = x[(size_t)c * 256 + pos];
        }
    }
}

// ---------------------------------------------------------------- RPN 3x3 conv (f32, 4 co/block, padded LDS)
__global__ __launch_bounds__(256) void k_rpn(const float* __restrict__ x,
                                             const float* __restrict__ rpn_w,
                                             float* __restrict__ fpart) {
    __shared__ float xs[8][18][18];
    const int coP = blockIdx.x, ks = blockIdx.y, tid = threadIdx.x;
    const int ty = tid >> 4, tx = tid & 15;
    const int co0 = coP * 4;
    for (int i = tid; i < 8 * 18 * 18; i += 256) ((float*)xs)[i] = 0.f;
    float acc[4] = {0.f, 0.f, 0.f, 0.f};
    for (int ch = 0; ch < 32; ++ch) {
        const int cib = ks * 256 + ch * 8;
        __syncthreads();
#pragma unroll
        for (int cc = 0; cc < 8; ++cc) xs[cc][ty + 1][tx + 1] = x[(size_t)(cib + cc) * 256 + tid];
        __syncthreads();
#pragma unroll
        for (int cc = 0; cc < 8; ++cc) {
            const int ci = cib + cc;
            float v[9];
#pragma unroll
            for (int t = 0; t < 9; ++t) v[t] = xs[cc][ty + t / 3][tx + t % 3];
            const float* wb = rpn_w + ((size_t)co0 * 2048 + ci) * 9;
#pragma unroll
            for (int o = 0; o < 4; ++o) {
                const float* w = wb + (size_t)o * 2048 * 9;
#pragma unroll
                for (int t = 0; t < 9; ++t) acc[o] = fmaf(v[t], w[t], acc[o]);
            }
        }
    }
#pragma unroll
    for (int o = 0; o < 4; ++o) fpart[((size_t)ks * 512 + co0 + o) * 256 + tid] = acc[o];
}

__global__ void k_rpn_reduce(const float* __restrict__ fpart, const float* __restrict__ rpn_b,
                             float* __restrict__ f) {
    const int i = blockIdx.x * 256 + threadIdx.x;
    float s = 0.f;
#pragma unroll
    for (int p = 0; p < 8; ++p) s += fpart[(size_t)p * 131072 + i];
    f[i] = fmaxf(s + rpn_b[i >> 8], 0.f);
}

// ---------------------------------------------------------------- heads: scores + decoded boxes (pipelined)
__global__ void k_head(const float* __restrict__ f, const float* __restrict__ cls_w,
                       const float* __restrict__ cls_b, const float* __restrict__ bbox_w,
                       const float* __restrict__ bbox_b, float* __restrict__ scores,
                       float* __restrict__ boxes) {
    const int a = blockIdx.x, pos = threadIdx.x;
    float o0 = 0, o1 = 0, d0 = 0, d1 = 0, d2 = 0, d3 = 0;
    const float* c0 = cls_w + (size_t)a * 512;
    const float* c1 = cls_w + (size_t)(9 + a) * 512;
    const float* b0p = bbox_w + (size_t)(4 * a) * 512;
    const float* b1p = b0p + 512;
    const float* b2p = b0p + 1024;
    const float* b3p = b0p + 1536;
    for (int ci = 0; ci < 512; ci += 8) {
        float fv[8];
#pragma unroll
        for (int j = 0; j < 8; ++j) fv[j] = f[(size_t)(ci + j) * 256 + pos];
#pragma unroll
        for (int j = 0; j < 8; ++j) {
            o0 = fmaf(c0[ci + j], fv[j], o0);
            o1 = fmaf(c1[ci + j], fv[j], o1);
            d0 = fmaf(b0p[ci + j], fv[j], d0);
            d1 = fmaf(b1p[ci + j], fv[j], d1);
            d2 = fmaf(b2p[ci + j], fv[j], d2);
            d3 = fmaf(b3p[ci + j], fv[j], d3);
        }
    }
    o0 += cls_b[a]; o1 += cls_b[9 + a];
    d0 += bbox_b[4 * a + 0]; d1 += bbox_b[4 * a + 1];
    d2 += bbox_b[4 * a + 2]; d3 += bbox_b[4 * a + 3];
    float mx = fmaxf(o0, o1);
    float e0 = expf(o0 - mx), e1 = expf(o1 - mx);
    float sc = e1 / (e0 + e1);
    int si = a / 3, ri = a % 3;
    float scale = (si == 0) ? 8.f : ((si == 1) ? 16.f : 32.f);
    float ratio = (ri == 0) ? 0.5f : ((ri == 1) ? 1.f : 2.f);
    float sq = sqrtf(ratio);
    float hw2 = (scale * sq) * 0.5f;
    float hh2 = (scale / sq) * 0.5f;
    int py = pos >> 4, px = pos & 15;
    float sx = (float)(px * 32), sy = (float)(py * 32);
    float a0 = sx - hw2, a1 = sy - hh2, a2 = sx + hw2, a3 = sy + hh2;
    float wa = a2 - a0, ha = a3 - a1;
    float cx = a0 + 0.5f * wa, cy = a1 + 0.5f * ha;
    float pxc = cx + d0 * wa, pyc = cy + d1 * ha;
    float pw = expf(d2) * wa, ph = expf(d3) * ha;
    int idx = a * 256 + pos;
    scores[idx] = sc;
    boxes[idx * 4 + 0] = pxc - 0.5f * pw;
    boxes[idx * 4 + 1] = pyc - 0.5f * ph;
    boxes[idx * 4 + 2] = pxc + 0.5f * pw;
    boxes[idx * 4 + 3] = pyc + 0.5f * ph;
}

// ---------------------------------------------------------------- stable descending rank sort
__global__ void k_sort(const float* __restrict__ scores, const float* __restrict__ boxes,
                       float* __restrict__ ssort, float* __restrict__ bsort) {
    const int i = blockIdx.x * 256 + threadIdx.x;
    const float si = scores[i];
    int rank = 0;
    for (int j = 0; j < 2304; ++j) {
        float sj = scores[j];
        rank += (sj > si) || (sj == si && j < i);
    }
    ssort[rank] = si;
    float4 bb = *(const float4*)(boxes + (size_t)i * 4);
    *(float4*)(bsort + (size_t)rank * 4) = bb;
}

// ---------------------------------------------------------------- suppression bitmask
__global__ void k_adj(const float* __restrict__ bsort, unsigned long long* __restrict__ adj) {
    const int i = blockIdx.x, lane = threadIdx.x;
    const float4 bi = *(const float4*)(bsort + (size_t)i * 4);
    const float ai = (bi.z - bi.x) * (bi.w - bi.y);
    for (int w = 0; w < 36; ++w) {
        int j = w * 64 + lane;
        bool sup = false;
        if (j < 2304 && j > i) {
            float4 bj = *(const float4*)(bsort + (size_t)j * 4);
            float aj = (bj.z - bj.x) * (bj.w - bj.y);
            float xx1 = fmaxf(bi.x, bj.x), yy1 = fmaxf(bi.y, bj.y);
            float xx2 = fminf(bi.z, bj.z), yy2 = fminf(bi.w, bj.w);
            float inter = fmaxf(xx2 - xx1, 0.f) * fmaxf(yy2 - yy1, 0.f);
            float iou = inter / (ai + aj - inter + 1e-9f);
            sup = iou > 0.5f;
        }
        unsigned long long m = __ballot(sup);
        if (lane == 0) adj[(size_t)i * 36 + w] = m;
    }
}

// ---------------------------------------------------------------- NMS: register bitmask skip-scan
__global__ void k_nms(const unsigned long long* __restrict__ adj, const float* __restrict__ bsort,
                      float* __restrict__ fb) {
    const int lane = threadIdx.x;
    unsigned long long r = (lane < 36) ? 0ULL : ~0ULL;
    int cnt = 0;
    for (int it = 0; it < 128; ++it) {
        unsigned long long inv = ~r;
        int local = inv ? (__ffsll((unsigned long long)inv) - 1) : 64;
        int cand = (local < 64) ? lane * 64 + local : (1 << 30);
#pragma unroll
        for (int d = 32; d; d >>= 1) cand = min(cand, __shfl_xor(cand, d));
        if (cand >= 2304) break;
        if (lane == 0) *(float4*)(fb + (size_t)cnt * 4) = *(const float4*)(bsort + (size_t)cand * 4);
        ++cnt;
        if (cnt == 100) break;
        unsigned long long a = (lane < 36) ? adj[(size_t)cand * 36 + lane] : 0ULL;
        r |= a;
        if (lane == (cand >> 6)) r |= 1ULL << (cand & 63);
    }
    for (int s2 = lane; s2 < 100; s2 += 64)
        if (s2 >= cnt) {
            float4 z = {0.f, 0.f, 0.f, 0.f};
            *(float4*)(fb + (size_t)s2 * 4) = z;
        }
}

// ---------------------------------------------------------------- ROI align -> flatA (fc1 frag order) + flatT [n][pos][c]
__global__ __launch_bounds__(256) void k_roi(const float* __restrict__ xt,
                                             const float* __restrict__ fb,
                                             ushort_t* __restrict__ flatA,
                                             ushort_t* __restrict__ flatT) {
    __shared__ int sxi0[14], sxi1[14], syi0[14], syi1[14];
    __shared__ float slx[14], sly[14];
    const int cg = blockIdx.x, n = blockIdx.y, tid = threadIdx.x;
    const float r0 = fb[n * 4 + 0] * 0.0625f, r1 = fb[n * 4 + 1] * 0.0625f;
    const float r2 = fb[n * 4 + 2] * 0.0625f, r3 = fb[n * 4 + 3] * 0.0625f;
    if (tid < 14) {
        float tt = ((float)tid + 0.5f) * (1.0f / 14.0f);
        float gx = r0 + tt * (r2 - r0);
        gx = fminf(fmaxf(gx, 0.f), 15.f);
        float x0f = floorf(gx);
        int x0 = (int)x0f;
        sxi0[tid] = x0; sxi1[tid] = min(x0 + 1, 15); slx[tid] = gx - x0f;
        float gy = r1 + tt * (r3 - r1);
        gy = fminf(fmaxf(gy, 0.f), 15.f);
        float y0f = floorf(gy);
        int y0 = (int)y0f;
        syi0[tid] = y0; syi1[tid] = min(y0 + 1, 15); sly[tid] = gy - y0f;
    }
    __syncthreads();
    const int c = cg * 256 + tid;
    for (int py = 0; py < 7; ++py) {
        for (int px = 0; px < 7; ++px) {
            float accv = 0.f;
#pragma unroll
            for (int a2 = 0; a2 < 2; ++a2) {
                int sy = py * 2 + a2;
                int y0 = syi0[sy], y1 = syi1[sy];
                float ly = sly[sy];
#pragma unroll
                for (int b2 = 0; b2 < 2; ++b2) {
                    int sx = px * 2 + b2;
                    int x0 = sxi0[sx], x1 = sxi1[sx];
                    float lx = slx[sx];
                    float v00 = xt[(size_t)(y0 * 16 + x0) * 2048 + c];
                    float v01 = xt[(size_t)(y0 * 16 + x1) * 2048 + c];
                    float v10 = xt[(size_t)(y1 * 16 + x0) * 2048 + c];
                    float v11 = xt[(size_t)(y1 * 16 + x1) * 2048 + c];
                    accv += (1.f - ly) * (1.f - lx) * v00 + (1.f - ly) * lx * v01 +
                            ly * (1.f - lx) * v10 + ly * lx * v11;
                }
            }
            ushort_t bv = f2bf(accv * 0.25f);
            int pos = py * 7 + px;
            flatT[((size_t)n * 49 + pos) * 2048 + c] = bv;
            int k = c * 49 + pos;
            flatA[((size_t)(k >> 5) * 112 + n) * 32 + (k & 31)] = bv;
        }
    }
}

// ---------------------------------------------------------------- fused: conv1 (77 blocks) + fc1 (1024 blocks, LDS-staged)
// fc1 K-loop: single barrier per K-step (guide's minimal 2-phase template) —
// stage(next) issued first, full compute phase overlaps the load, one
// vmcnt(0)+barrier drain at the END of the step.
__global__ __launch_bounds__(256, 4) void k_big(const ushort_t* __restrict__ flatA,
                                                const ushort_t* __restrict__ flatT,
                                                const float* __restrict__ Wc,
                                                const float* __restrict__ Wb,
                                                float* __restrict__ part,
                                                const ushort_t* __restrict__ wAf,
                                                const float* __restrict__ m1_b,
                                                ushort_t* __restrict__ m1outT) {
    __shared__ float wlds[2][32][128];   // 32 KB double-buffered W tile
    const int bid = blockIdx.x, tid = threadIdx.x;
    const int wave = tid >> 6, lane = tid & 63, l15 = lane & 15, lg = lane >> 4;
    const f32x4 zz = {0.f, 0.f, 0.f, 0.f};
    if (bid < 77) {
        // ---- mask conv1 3x3 implicit GEMM (M=256 co, N=64 cols, K=2048*9)
        const int nb = bid;
        int nn[4], ppy[4], ppx[4], colv[4];
#pragma unroll
        for (int nt = 0; nt < 4; ++nt) {
            int col = nb * 64 + nt * 16 + l15;
            colv[nt] = col;
            int n = col / 49;
            int pos = col - n * 49;
            nn[nt] = n;
            ppy[nt] = pos / 7;
            ppx[nt] = pos - (pos / 7) * 7;
        }
        f32x4 acc[4][4];
#pragma unroll
        for (int a = 0; a < 4; ++a)
#pragma unroll
            for (int b = 0; b < 4; ++b) acc[a][b] = zz;
        bf16x8 zfrag;
#pragma unroll
        for (int j = 0; j < 8; ++j) zfrag[j] = 0;
        for (int tap = 0; tap < 9; ++tap) {
            const int ty = tap / 3 - 1, tx = tap % 3 - 1;
            int val[4];
            size_t bofs[4];
#pragma unroll
            for (int nt = 0; nt < 4; ++nt) {
                int iy = ppy[nt] + ty, ix = ppx[nt] + tx;
                val[nt] = (iy >= 0 && iy < 7 && ix >= 0 && ix < 7);
                bofs[nt] = ((size_t)nn[nt] * 49 + iy * 7 + ix) * 2048;
            }
            for (int cis = 0; cis < 64; ++cis) {
                const int kq = cis * 32 + lg * 8;
                bf16x8 a[4];
#pragma unroll
                for (int mt = 0; mt < 4; ++mt)
                    a[mt] = *(const bf16x8*)(wAf +
                            ((size_t)((tap * 16 + wave * 4 + mt) * 64 + cis) * 64 + lane) * 8);
                bf16x8 b[4];
#pragma unroll
                for (int nt = 0; nt < 4; ++nt)
                    b[nt] = val[nt] ? *(const bf16x8*)(flatT + bofs[nt] + kq) : zfrag;
#pragma unroll
                for (int nt = 0; nt < 4; ++nt)
#pragma unroll
                    for (int mt = 0; mt < 4; ++mt)
                        acc[mt][nt] = __builtin_amdgcn_mfma_f32_16x16x32_bf16(a[mt], b[nt], acc[mt][nt], 0, 0, 0);
            }
        }
#pragma unroll
        for (int mt = 0; mt < 4; ++mt)
#pragma unroll
            for (int nt = 0; nt < 4; ++nt) {
                int co0 = wave * 64 + mt * 16 + lg * 4;
                ushort_t v[4];
#pragma unroll
                for (int r = 0; r < 4; ++r)
                    v[r] = f2bf(fmaxf(acc[mt][nt][r] + m1_b[co0 + r], 0.f));
                uint2 u;
                u.x = (uint32)v[0] | ((uint32)v[1] << 16);
                u.y = (uint32)v[2] | ((uint32)v[3] << 16);
                *(uint2*)(m1outT + (size_t)colv[nt] * 256 + co0) = u;
            }
        return;
    }
    // ---- fc1: LDS-staged W (global_load_lds x16), 16 kc x 2 br x 32 col-tiles.
    //      XCD grouping: kc in {2x, 2x+1} for both branches -> 2.8MB flatA L2-resident/XCD.
    const int h = bid - 77;
    const int x = h & 7, t = h >> 3;
    const int colTile = t >> 2, rem = t & 3;
    const int kc = x * 2 + (rem & 1), br = rem >> 1;
    const float* W = br ? Wb : Wc;
    const int ncol0 = colTile * 128 + wave * 32;
    const int k0 = kc * 6272;                    // 196 K-steps of 32
    const float* wbase = W + (size_t)k0 * 4096 + colTile * 128;
    const int srow = lane >> 5, scol = (lane & 31) * 4;

    auto stage = [&](int buf, int s) {
        const float* g0 = wbase + ((size_t)(s * 32 + wave * 8 + srow)) * 4096 + scol;
#pragma unroll
        for (int q = 0; q < 4; ++q) {
            const float* g = g0 + (size_t)(q * 2) * 4096;
            float* l = &wlds[buf][wave * 8 + q * 2][0];
            __builtin_amdgcn_global_load_lds((glob_uint*)g, (lds_uint*)l, 16, 0, 0);
        }
    };

    f32x4 acc0[7], acc1[7];
#pragma unroll
    for (int tt = 0; tt < 7; ++tt) { acc0[tt] = zz; acc1[tt] = zz; }

    stage(0, 0);
    __syncthreads();                    // prologue drain: buf0 ready
    const ushort_t* ap = flatA + ((size_t)(kc * 196) * 112 + l15) * 32 + lg * 8;
    for (int s = 0; s < 196; ++s) {
        const int b = s & 1;
        if (s + 1 < 196) stage(b ^ 1, s + 1);   // issue next tile (stays in flight all step)
        bf16x8 af[7];
#pragma unroll
        for (int tt = 0; tt < 7; ++tt) af[tt] = *(const bf16x8*)(ap + (size_t)tt * 512);
        const float* wrow = &wlds[b][lg * 8][wave * 32 + l15];
        BWU b0u, b1u;
#pragma unroll
        for (int i = 0; i < 4; ++i) {
            float w0a = wrow[(2 * i) * 128], w0b = wrow[(2 * i + 1) * 128];
            float w1a = wrow[(2 * i) * 128 + 16], w1b = wrow[(2 * i + 1) * 128 + 16];
            asm("v_cvt_pk_bf16_f32 %0, %1, %2" : "=v"(b0u.u[i]) : "v"(w0a), "v"(w0b));
            asm("v_cvt_pk_bf16_f32 %0, %1, %2" : "=v"(b1u.u[i]) : "v"(w1a), "v"(w1b));
        }
#pragma unroll
        for (int tt = 0; tt < 7; ++tt) {
            acc0[tt] = __builtin_amdgcn_mfma_f32_16x16x32_bf16(af[tt], b0u.v8, acc0[tt], 0, 0, 0);
            acc1[tt] = __builtin_amdgcn_mfma_f32_16x16x32_bf16(af[tt], b1u.v8, acc1[tt], 0, 0, 0);
        }
        ap += 3584;
        __syncthreads();                // single drain+barrier: buf b^1 ready for next step
    }
    float* pb = part + (size_t)(br * 16 + kc) * 112 * 4096;
#pragma unroll
    for (int tt = 0; tt < 7; ++tt)
#pragma unroll
        for (int r = 0; r < 4; ++r) {
            int m = tt * 16 + lg * 4 + r;
            pb[(size_t)m * 4096 + ncol0 + l15] = acc0[tt][r];
            pb[(size_t)m * 4096 + ncol0 + 16 + l15] = acc1[tt][r];
        }
}

// ---------------------------------------------------------------- fused fc1-reduce + fc2 heads (2 k-halves x 8 accs)
__global__ __launch_bounds__(256) void k_fc2(const float* __restrict__ part,
                                             const float* __restrict__ fc1c_b,
                                             const float* __restrict__ fc1b_b,
                                             const float* __restrict__ Wc,
                                             const float* __restrict__ bc,
                                             const float* __restrict__ Wb,
                                             const float* __restrict__ bb,
                                             float* __restrict__ out) {
    __shared__ float h_s[2][4096];
    __shared__ float ph[2][91];
    __shared__ float pbx[2][4];
    const int m = blockIdx.x, tid = threadIdx.x;
    for (int i = tid; i < 8192; i += 256) {
        int br = i >> 12, col = i & 4095;
        float s = br ? fc1b_b[col] : fc1c_b[col];
#pragma unroll
        for (int p = 0; p < 16; ++p) s += part[((size_t)(br * 16 + p) * 112 + m) * 4096 + col];
        h_s[br][col] = fmaxf(s, 0.f);
    }
    __syncthreads();
    const int half = tid >> 7, col = tid & 127;
    if (col < 91) {
        const float* hrow = &h_s[0][half * 2048];
        const float* wp = Wc + (size_t)half * 2048 * 91 + col;
        float a0 = 0, a1 = 0, a2 = 0, a3 = 0, a4 = 0, a5 = 0, a6 = 0, a7 = 0;
        for (int k = 0; k < 2048; k += 8) {
            a0 = fmaf(hrow[k],     wp[(size_t)k * 91], a0);
            a1 = fmaf(hrow[k + 1], wp[(size_t)(k + 1) * 91], a1);
            a2 = fmaf(hrow[k + 2], wp[(size_t)(k + 2) * 91], a2);
            a3 = fmaf(hrow[k + 3], wp[(size_t)(k + 3) * 91], a3);
            a4 = fmaf(hrow[k + 4], wp[(size_t)(k + 4) * 91], a4);
            a5 = fmaf(hrow[k + 5], wp[(size_t)(k + 5) * 91], a5);
            a6 = fmaf(hrow[k + 6], wp[(size_t)(k + 6) * 91], a6);
            a7 = fmaf(hrow[k + 7], wp[(size_t)(k + 7) * 91], a7);
        }
        ph[half][col] = ((a0 + a1) + (a2 + a3)) + ((a4 + a5) + (a6 + a7));
    } else if (col >= 96 && col < 100) {
        int bcol = col - 96;
        const float* hrow = &h_s[1][half * 2048];
        const float* wp = Wb + (size_t)half * 2048 * 4 + bcol;
        float a0 = 0, a1 = 0, a2 = 0, a3 = 0, a4 = 0, a5 = 0, a6 = 0, a7 = 0;
        for (int k = 0; k < 2048; k += 8) {
            a0 = fmaf(hrow[k],     wp[(size_t)k * 4], a0);
            a1 = fmaf(hrow[k + 1], wp[(size_t)(k + 1) * 4], a1);
            a2 = fmaf(hrow[k + 2], wp[(size_t)(k + 2) * 4], a2);
            a3 = fmaf(hrow[k + 3], wp[(size_t)(k + 3) * 4], a3);
            a4 = fmaf(hrow[k + 4], wp[(size_t)(k + 4) * 4], a4);
            a5 = fmaf(hrow[k + 5], wp[(size_t)(k + 5) * 4], a5);
            a6 = fmaf(hrow[k + 6], wp[(size_t)(k + 6) * 4], a6);
            a7 = fmaf(hrow[k + 7], wp[(size_t)(k + 7) * 4], a7);
        }
        pbx[half][bcol] = ((a0 + a1) + (a2 + a3)) + ((a4 + a5) + (a6 + a7));
    }
    __syncthreads();
    if (tid < 91) out[m * 91 + tid] = bc[tid] + ph[0][tid] + ph[1][tid];
    else if (tid >= 96 && tid < 100) {
        int bcol = tid - 96;
        out[9100 + m * 4 + bcol] = bb[bcol] + pbx[0][bcol] + pbx[1][bcol];
    }
}

// ---------------------------------------------------------------- transposed conv 2x2 s2 as GEMM
__global__ __launch_bounds__(256) void k_up(const ushort_t* __restrict__ m1outT,
                                            const ushort_t* __restrict__ wA2f,
                                            ushort_t* __restrict__ upT) {
    const int nb = blockIdx.x, cq = blockIdx.y, tid = threadIdx.x;
    const int wave = tid >> 6, lane = tid & 63, l15 = lane & 15, lg = lane >> 4;
    int colv[4];
#pragma unroll
    for (int nt = 0; nt < 4; ++nt) colv[nt] = nb * 64 + nt * 16 + l15;
    f32x4 acc[4][4];
    const f32x4 zz = {0.f, 0.f, 0.f, 0.f};
#pragma unroll
    for (int a = 0; a < 4; ++a)
#pragma unroll
        for (int b = 0; b < 4; ++b) acc[a][b] = zz;
    for (int cis = 0; cis < 8; ++cis) {
        const int kq = cis * 32 + lg * 8;
        bf16x8 a[4];
#pragma unroll
        for (int mt = 0; mt < 4; ++mt)
            a[mt] = *(const bf16x8*)(wA2f +
                    ((size_t)((cq * 16 + wave * 4 + mt) * 8 + cis) * 64 + lane) * 8);
        bf16x8 b[4];
#pragma unroll
        for (int nt = 0; nt < 4; ++nt)
            b[nt] = *(const bf16x8*)(m1outT + (size_t)colv[nt] * 256 + kq);
#pragma unroll
        for (int nt = 0; nt < 4; ++nt)
#pragma unroll
            for (int mt = 0; mt < 4; ++mt)
                acc[mt][nt] = __builtin_amdgcn_mfma_f32_16x16x32_bf16(a[mt], b[nt], acc[mt][nt], 0, 0, 0);
    }
#pragma unroll
    for (int mt = 0; mt < 4; ++mt)
#pragma unroll
        for (int nt = 0; nt < 4; ++nt) {
            int rb = (cq * 16 + wave * 4 + mt) * 16 + lg * 4;
            ushort_t v[4];
#pragma unroll
            for (int r = 0; r < 4; ++r) v[r] = f2bf(acc[mt][nt][r]);
            uint2 u;
            u.x = (uint32)v[0] | ((uint32)v[1] << 16);
            u.y = (uint32)v[2] | ((uint32)v[3] << 16);
            *(uint2*)(upT + (size_t)colv[nt] * 1024 + rb) = u;
        }
}

// ---------------------------------------------------------------- final mask 1x1 conv (+bias/relu of up)
__global__ void k_mask(const ushort_t* __restrict__ upT, const float* __restrict__ mt_b,
                       const float* __restrict__ m2_w, const float* __restrict__ m2_b,
                       float* __restrict__ out) {
    const int n = blockIdx.x, t = threadIdx.x;
    if (t >= 196) return;
    const int ys = t / 14, xs = t % 14;
    const int ro = (ys & 1) * 2 + (xs & 1);
    const int col = n * 49 + (ys >> 1) * 7 + (xs >> 1);
    const ushort_t* up0 = upT + (size_t)col * 1024 + ro;
    float a0 = m2_b[0], a1 = 0.f, a2 = 0.f, a3 = 0.f;
#pragma unroll 4
    for (int o = 0; o < 256; o += 4) {
        a0 = fmaf(m2_w[o],     fmaxf(bf2f(up0[(o) * 4]) + mt_b[o], 0.f), a0);
        a1 = fmaf(m2_w[o + 1], fmaxf(bf2f(up0[(o + 1) * 4]) + mt_b[o + 1], 0.f), a1);
        a2 = fmaf(m2_w[o + 2], fmaxf(bf2f(up0[(o + 2) * 4]) + mt_b[o + 2], 0.f), a2);
        a3 = fmaf(m2_w[o + 3], fmaxf(bf2f(up0[(o + 3) * 4]) + mt_b[o + 3], 0.f), a3);
    }
    out[9500 + n * 196 + t] = (a0 + a1) + (a2 + a3);
}

// ================================================================ launch
extern "C" void kernel_launch(void* const* d_in, const int* in_sizes, int n_in,
                              void* d_out, int out_size, void* d_ws, size_t ws_size,
                              hipStream_t stream) {
    const float* x      = (const float*)d_in[0];
    const float* rpn_w  = (const float*)d_in[1];
    const float* rpn_b  = (const float*)d_in[2];
    const float* cls_w  = (const float*)d_in[3];
    const float* cls_b  = (const float*)d_in[4];
    const float* bbox_w = (const float*)d_in[5];
    const float* bbox_b = (const float*)d_in[6];
    const float* fc1c_w = (const float*)d_in[7];
    const float* fc1c_b = (const float*)d_in[8];
    const float* fc2c_w = (const float*)d_in[9];
    const float* fc2c_b = (const float*)d_in[10];
    const float* fc1b_w = (const float*)d_in[11];
    const float* fc1b_b = (const float*)d_in[12];
    const float* fc2b_w = (const float*)d_in[13];
    const float* fc2b_b = (const float*)d_in[14];
    const float* m1_w   = (const float*)d_in[15];
    const float* m1_b   = (const float*)d_in[16];
    const float* mt_w   = (const float*)d_in[17];
    const float* mt_b   = (const float*)d_in[18];
    const float* m2_w   = (const float*)d_in[19];
    const float* m2_b   = (const float*)d_in[20];
    float* out = (float*)d_out;

    char* ws = (char*)d_ws;
    size_t off = 0;
    auto take = [&](size_t nbytes) -> char* {
        char* p = ws + off;
        off += (nbytes + 255) & ~(size_t)255;
        return p;
    };
    float* xt      = (float*)take(2097152);                 // 256 x 2048 f32
    float* fpart   = (float*)take(4194304);                 // 8 x 512 x 256 f32
    float* f       = (float*)take(524288);                  // 512 x 256 f32
    float* scores  = (float*)take(9216);
    float* boxes   = (float*)take(36864);
    float* ssort   = (float*)take(9216);
    float* bsort   = (float*)take(36864);
    unsigned long long* adj = (unsigned long long*)take(663552);  // 2304 x 36 u64
    float* fb      = (float*)take(1600);                    // 100 x 4 f32
    ushort_t* flatA = (ushort_t*)take(22478848);            // 3136 x 112 x 32 bf16
    ushort_t* flatT = (ushort_t*)take(20471808);            // 102 x 49 x 2048 bf16
    float* part1   = (float*)take(58720256);                // 2 x 16 x 112 x 4096 f32
    ushort_t* wAf  = (ushort_t*)take(9437184);              // 9x16x64x64x8 bf16
    ushort_t* m1outT = (ushort_t*)take(2523136);            // 4928 x 256 bf16
    ushort_t* wA2f = (ushort_t*)take(524288);               // 64x8x64x8 bf16
    ushort_t* upT  = (ushort_t*)part1;                      // reuse (part1 dead after k_fc2)

    k_prep<<<1536, 256, 0, stream>>>(m1_w, mt_w, x, wAf, wA2f, xt);
    k_rpn<<<dim3(128, 8), 256, 0, stream>>>(x, rpn_w, fpart);
    k_rpn_reduce<<<512, 256, 0, stream>>>(fpart, rpn_b, f);
    k_head<<<9, 256, 0, stream>>>(f, cls_w, cls_b, bbox_w, bbox_b, scores, boxes);
    k_sort<<<9, 256, 0, stream>>>(scores, boxes, ssort, bsort);
    k_adj<<<2304, 64, 0, stream>>>(bsort, adj);
    k_nms<<<1, 64, 0, stream>>>(adj, bsort, fb);
    k_roi<<<dim3(8, 100), 256, 0, stream>>>(xt, fb, flatA, flatT);
    k_big<<<1101, 256, 0, stream>>>(flatA, flatT, fc1c_w, fc1b_w, part1, wAf, m1_b, m1outT);
    k_fc2<<<100, 256, 0, stream>>>(part1, fc1c_b, fc1b_b, fc2c_w, fc2c_b, fc2b_w, fc2b_b, out);
    k_up<<<dim3(77, 4), 256, 0, stream>>>(m1outT, wA2f, upT);
    k_mask<<<100, 256, 0, stream>>>(upT, mt_b, m2_w, m2_b, out);
}

// Round 8
// 1486.751 us; speedup vs baseline: 1.0367x; 1.0367x over previous
//
#include <hip/hip_runtime.h>

#define DEVFN __device__ __forceinline__

typedef unsigned short ushort_t;
typedef unsigned int uint32;
typedef __attribute__((ext_vector_type(8))) short bf16x8;
typedef __attribute__((ext_vector_type(4))) float f32x4;

typedef __attribute__((address_space(3))) unsigned int lds_uint;
typedef const __attribute__((address_space(1))) unsigned int glob_uint;

DEVFN ushort_t f2bf(float x) {
    uint32 b = __float_as_uint(x);
    uint32 r = (b + 0x7FFFu + ((b >> 16) & 1u)) >> 16;
    return (ushort_t)r;
}
DEVFN float bf2f(ushort_t u) { return __uint_as_float(((uint32)u) << 16); }

union BWU { uint32 u[4]; bf16x8 v8; };

// ---------------------------------------------------------------- fused: RPN conv (1024 blocks) + prep (1536 blocks)
__global__ __launch_bounds__(256) void k_pre(const float* __restrict__ x,
                                             const float* __restrict__ rpn_w,
                                             float* __restrict__ fpart,
                                             const float* __restrict__ m1_w,
                                             const float* __restrict__ mt_w,
                                             ushort_t* __restrict__ wAf,
                                             ushort_t* __restrict__ wA2f,
                                             float* __restrict__ xt) {
    const int bid = blockIdx.x, tid = threadIdx.x;
    if (bid < 1024) {
        // ---- RPN 3x3 conv (f32, 4 co/block, padded LDS)
        __shared__ float xs[8][18][18];
        const int coP = bid & 127, ks = bid >> 7;
        const int ty = tid >> 4, tx = tid & 15;
        const int co0 = coP * 4;
        for (int i = tid; i < 8 * 18 * 18; i += 256) ((float*)xs)[i] = 0.f;
        float acc[4] = {0.f, 0.f, 0.f, 0.f};
        for (int ch = 0; ch < 32; ++ch) {
            const int cib = ks * 256 + ch * 8;
            __syncthreads();
#pragma unroll
            for (int cc = 0; cc < 8; ++cc) xs[cc][ty + 1][tx + 1] = x[(size_t)(cib + cc) * 256 + tid];
            __syncthreads();
#pragma unroll
            for (int cc = 0; cc < 8; ++cc) {
                const int ci = cib + cc;
                float v[9];
#pragma unroll
                for (int t = 0; t < 9; ++t) v[t] = xs[cc][ty + t / 3][tx + t % 3];
                const float* wb = rpn_w + ((size_t)co0 * 2048 + ci) * 9;
#pragma unroll
                for (int o = 0; o < 4; ++o) {
                    const float* w = wb + (size_t)o * 2048 * 9;
#pragma unroll
                    for (int t = 0; t < 9; ++t) acc[o] = fmaf(v[t], w[t], acc[o]);
                }
            }
        }
#pragma unroll
        for (int o = 0; o < 4; ++o) fpart[((size_t)ks * 512 + co0 + o) * 256 + tid] = acc[o];
        return;
    }
    const int pb = bid - 1024;
    if (pb < 256) {
        const int p = pb * 4 + (tid >> 6);
        const int lane = tid & 63, l15 = lane & 15, lg = lane >> 4;
        const int cot = p >> 6, cis = p & 63;
        const int co = cot * 16 + l15, k0 = cis * 32 + lg * 8;
        const float* src = m1_w + ((size_t)co * 2048 + k0) * 9;
        float v[72];
#pragma unroll
        for (int i = 0; i < 72; ++i) v[i] = src[i];
#pragma unroll
        for (int tap = 0; tap < 9; ++tap) {
            ushort_t* dst = wAf + ((size_t)((tap * 16 + cot) * 64 + cis) * 512) + lane * 8;
            ushort_t t8[8];
#pragma unroll
            for (int j = 0; j < 8; ++j) t8[j] = f2bf(v[j * 9 + tap]);
            uint4 u;
            u.x = (uint32)t8[0] | ((uint32)t8[1] << 16);
            u.y = (uint32)t8[2] | ((uint32)t8[3] << 16);
            u.z = (uint32)t8[4] | ((uint32)t8[5] << 16);
            u.w = (uint32)t8[6] | ((uint32)t8[7] << 16);
            *(uint4*)dst = u;
        }
    } else if (pb < 1280) {
        int idx = (pb - 256) * 256 + tid;
        int j = idx & 7, lane = (idx >> 3) & 63, cis = (idx >> 9) & 7, cot = idx >> 12;
        int row = cot * 16 + (lane & 15);
        int c = cis * 32 + (lane >> 4) * 8 + j;
        int o = row >> 2, ij = row & 3;
        wA2f[idx] = f2bf(mt_w[((size_t)c * 256 + o) * 4 + ij]);
    } else {
        int pos = pb - 1280;
        for (int i = 0; i < 8; ++i) {
            int c = tid + i * 256;
            xt[(size_t)pos * 2048 + c] = x[(size_t)c * 256 + pos];
        }
    }
}

__global__ void k_rpn_reduce(const float* __restrict__ fpart, const float* __restrict__ rpn_b,
                             float* __restrict__ f) {
    const int i = blockIdx.x * 256 + threadIdx.x;
    float s = 0.f;
#pragma unroll
    for (int p = 0; p < 8; ++p) s += fpart[(size_t)p * 131072 + i];
    f[i] = fmaxf(s + rpn_b[i >> 8], 0.f);
}

// ---------------------------------------------------------------- heads: scores + decoded boxes (pipelined)
__global__ void k_head(const float* __restrict__ f, const float* __restrict__ cls_w,
                       const float* __restrict__ cls_b, const float* __restrict__ bbox_w,
                       const float* __restrict__ bbox_b, float* __restrict__ scores,
                       float* __restrict__ boxes) {
    const int a = blockIdx.x, pos = threadIdx.x;
    float o0 = 0, o1 = 0, d0 = 0, d1 = 0, d2 = 0, d3 = 0;
    const float* c0 = cls_w + (size_t)a * 512;
    const float* c1 = cls_w + (size_t)(9 + a) * 512;
    const float* b0p = bbox_w + (size_t)(4 * a) * 512;
    const float* b1p = b0p + 512;
    const float* b2p = b0p + 1024;
    const float* b3p = b0p + 1536;
    for (int ci = 0; ci < 512; ci += 8) {
        float fv[8];
#pragma unroll
        for (int j = 0; j < 8; ++j) fv[j] = f[(size_t)(ci + j) * 256 + pos];
#pragma unroll
        for (int j = 0; j < 8; ++j) {
            o0 = fmaf(c0[ci + j], fv[j], o0);
            o1 = fmaf(c1[ci + j], fv[j], o1);
            d0 = fmaf(b0p[ci + j], fv[j], d0);
            d1 = fmaf(b1p[ci + j], fv[j], d1);
            d2 = fmaf(b2p[ci + j], fv[j], d2);
            d3 = fmaf(b3p[ci + j], fv[j], d3);
        }
    }
    o0 += cls_b[a]; o1 += cls_b[9 + a];
    d0 += bbox_b[4 * a + 0]; d1 += bbox_b[4 * a + 1];
    d2 += bbox_b[4 * a + 2]; d3 += bbox_b[4 * a + 3];
    float mx = fmaxf(o0, o1);
    float e0 = expf(o0 - mx), e1 = expf(o1 - mx);
    float sc = e1 / (e0 + e1);
    int si = a / 3, ri = a % 3;
    float scale = (si == 0) ? 8.f : ((si == 1) ? 16.f : 32.f);
    float ratio = (ri == 0) ? 0.5f : ((ri == 1) ? 1.f : 2.f);
    float sq = sqrtf(ratio);
    float hw2 = (scale * sq) * 0.5f;
    float hh2 = (scale / sq) * 0.5f;
    int py = pos >> 4, px = pos & 15;
    float sx = (float)(px * 32), sy = (float)(py * 32);
    float a0 = sx - hw2, a1 = sy - hh2, a2 = sx + hw2, a3 = sy + hh2;
    float wa = a2 - a0, ha = a3 - a1;
    float cx = a0 + 0.5f * wa, cy = a1 + 0.5f * ha;
    float pxc = cx + d0 * wa, pyc = cy + d1 * ha;
    float pw = expf(d2) * wa, ph = expf(d3) * ha;
    int idx = a * 256 + pos;
    scores[idx] = sc;
    boxes[idx * 4 + 0] = pxc - 0.5f * pw;
    boxes[idx * 4 + 1] = pyc - 0.5f * ph;
    boxes[idx * 4 + 2] = pxc + 0.5f * pw;
    boxes[idx * 4 + 3] = pyc + 0.5f * ph;
}

// ---------------------------------------------------------------- stable descending rank sort
__global__ void k_sort(const float* __restrict__ scores, const float* __restrict__ boxes,
                       float* __restrict__ ssort, float* __restrict__ bsort) {
    const int i = blockIdx.x * 256 + threadIdx.x;
    const float si = scores[i];
    int rank = 0;
    for (int j = 0; j < 2304; ++j) {
        float sj = scores[j];
        rank += (sj > si) || (sj == si && j < i);
    }
    ssort[rank] = si;
    float4 bb = *(const float4*)(boxes + (size_t)i * 4);
    *(float4*)(bsort + (size_t)rank * 4) = bb;
}

// ---------------------------------------------------------------- suppression bitmask
__global__ void k_adj(const float* __restrict__ bsort, unsigned long long* __restrict__ adj) {
    const int i = blockIdx.x, lane = threadIdx.x;
    const float4 bi = *(const float4*)(bsort + (size_t)i * 4);
    const float ai = (bi.z - bi.x) * (bi.w - bi.y);
    for (int w = 0; w < 36; ++w) {
        int j = w * 64 + lane;
        bool sup = false;
        if (j < 2304 && j > i) {
            float4 bj = *(const float4*)(bsort + (size_t)j * 4);
            float aj = (bj.z - bj.x) * (bj.w - bj.y);
            float xx1 = fmaxf(bi.x, bj.x), yy1 = fmaxf(bi.y, bj.y);
            float xx2 = fminf(bi.z, bj.z), yy2 = fminf(bi.w, bj.w);
            float inter = fmaxf(xx2 - xx1, 0.f) * fmaxf(yy2 - yy1, 0.f);
            float iou = inter / (ai + aj - inter + 1e-9f);
            sup = iou > 0.5f;
        }
        unsigned long long m = __ballot(sup);
        if (lane == 0) adj[(size_t)i * 36 + w] = m;
    }
}

// ---------------------------------------------------------------- NMS: register bitmask skip-scan
__global__ void k_nms(const unsigned long long* __restrict__ adj, const float* __restrict__ bsort,
                      float* __restrict__ fb) {
    const int lane = threadIdx.x;
    unsigned long long r = (lane < 36) ? 0ULL : ~0ULL;
    int cnt = 0;
    for (int it = 0; it < 128; ++it) {
        unsigned long long inv = ~r;
        int local = inv ? (__ffsll((unsigned long long)inv) - 1) : 64;
        int cand = (local < 64) ? lane * 64 + local : (1 << 30);
#pragma unroll
        for (int d = 32; d; d >>= 1) cand = min(cand, __shfl_xor(cand, d));
        if (cand >= 2304) break;
        if (lane == 0) *(float4*)(fb + (size_t)cnt * 4) = *(const float4*)(bsort + (size_t)cand * 4);
        ++cnt;
        if (cnt == 100) break;
        unsigned long long a = (lane < 36) ? adj[(size_t)cand * 36 + lane] : 0ULL;
        r |= a;
        if (lane == (cand >> 6)) r |= 1ULL << (cand & 63);
    }
    for (int s2 = lane; s2 < 100; s2 += 64)
        if (s2 >= cnt) {
            float4 z = {0.f, 0.f, 0.f, 0.f};
            *(float4*)(fb + (size_t)s2 * 4) = z;
        }
}

// ---------------------------------------------------------------- ROI align -> flatA (fc1 frag order) + flatT [n][pos][c]
__global__ __launch_bounds__(256) void k_roi(const float* __restrict__ xt,
                                             const float* __restrict__ fb,
                                             ushort_t* __restrict__ flatA,
                                             ushort_t* __restrict__ flatT) {
    __shared__ int sxi0[14], sxi1[14], syi0[14], syi1[14];
    __shared__ float slx[14], sly[14];
    const int cg = blockIdx.x, n = blockIdx.y, tid = threadIdx.x;
    const float r0 = fb[n * 4 + 0] * 0.0625f, r1 = fb[n * 4 + 1] * 0.0625f;
    const float r2 = fb[n * 4 + 2] * 0.0625f, r3 = fb[n * 4 + 3] * 0.0625f;
    if (tid < 14) {
        float tt = ((float)tid + 0.5f) * (1.0f / 14.0f);
        float gx = r0 + tt * (r2 - r0);
        gx = fminf(fmaxf(gx, 0.f), 15.f);
        float x0f = floorf(gx);
        int x0 = (int)x0f;
        sxi0[tid] = x0; sxi1[tid] = min(x0 + 1, 15); slx[tid] = gx - x0f;
        float gy = r1 + tt * (r3 - r1);
        gy = fminf(fmaxf(gy, 0.f), 15.f);
        float y0f = floorf(gy);
        int y0 = (int)y0f;
        syi0[tid] = y0; syi1[tid] = min(y0 + 1, 15); sly[tid] = gy - y0f;
    }
    __syncthreads();
    const int c = cg * 256 + tid;
    for (int py = 0; py < 7; ++py) {
        for (int px = 0; px < 7; ++px) {
            float accv = 0.f;
#pragma unroll
            for (int a2 = 0; a2 < 2; ++a2) {
                int sy = py * 2 + a2;
                int y0 = syi0[sy], y1 = syi1[sy];
                float ly = sly[sy];
#pragma unroll
                for (int b2 = 0; b2 < 2; ++b2) {
                    int sx = px * 2 + b2;
                    int x0 = sxi0[sx], x1 = sxi1[sx];
                    float lx = slx[sx];
                    float v00 = xt[(size_t)(y0 * 16 + x0) * 2048 + c];
                    float v01 = xt[(size_t)(y0 * 16 + x1) * 2048 + c];
                    float v10 = xt[(size_t)(y1 * 16 + x0) * 2048 + c];
                    float v11 = xt[(size_t)(y1 * 16 + x1) * 2048 + c];
                    accv += (1.f - ly) * (1.f - lx) * v00 + (1.f - ly) * lx * v01 +
                            ly * (1.f - lx) * v10 + ly * lx * v11;
                }
            }
            ushort_t bv = f2bf(accv * 0.25f);
            int pos = py * 7 + px;
            flatT[((size_t)n * 49 + pos) * 2048 + c] = bv;
            int k = c * 49 + pos;
            flatA[((size_t)(k >> 5) * 112 + n) * 32 + (k & 31)] = bv;
        }
    }
}

// ---------------------------------------------------------------- fused: conv1 (77 blocks) + fc1 (1024 blocks)
// fc1 K-loop: counted-vmcnt pipeline (T3+T4). af issued BEFORE stage (vmcnt is
// in-order), then s_waitcnt vmcnt(11) keeps the 11 newest (af(s+1)x7 +
// stage(s+1)x4) in flight across raw s_barrier.
__global__ __launch_bounds__(256) void k_big(const ushort_t* __restrict__ flatA,
                                             const ushort_t* __restrict__ flatT,
                                             const float* __restrict__ Wc,
                                             const float* __restrict__ Wb,
                                             float* __restrict__ part,
                                             const ushort_t* __restrict__ wAf,
                                             const float* __restrict__ m1_b,
                                             ushort_t* __restrict__ m1outT) {
    __shared__ float wlds[2][32][128];   // 32 KB double-buffered W tile
    const int bid = blockIdx.x, tid = threadIdx.x;
    const int wave = tid >> 6, lane = tid & 63, l15 = lane & 15, lg = lane >> 4;
    const f32x4 zz = {0.f, 0.f, 0.f, 0.f};
    if (bid < 77) {
        // ---- mask conv1 3x3 implicit GEMM (M=256 co, N=64 cols, K=2048*9)
        const int nb = bid;
        int nn[4], ppy[4], ppx[4], colv[4];
#pragma unroll
        for (int nt = 0; nt < 4; ++nt) {
            int col = nb * 64 + nt * 16 + l15;
            colv[nt] = col;
            int n = col / 49;
            int pos = col - n * 49;
            nn[nt] = n;
            ppy[nt] = pos / 7;
            ppx[nt] = pos - (pos / 7) * 7;
        }
        f32x4 acc[4][4];
#pragma unroll
        for (int a = 0; a < 4; ++a)
#pragma unroll
            for (int b = 0; b < 4; ++b) acc[a][b] = zz;
        bf16x8 zfrag;
#pragma unroll
        for (int j = 0; j < 8; ++j) zfrag[j] = 0;
        for (int tap = 0; tap < 9; ++tap) {
            const int ty = tap / 3 - 1, tx = tap % 3 - 1;
            int val[4];
            size_t bofs[4];
#pragma unroll
            for (int nt = 0; nt < 4; ++nt) {
                int iy = ppy[nt] + ty, ix = ppx[nt] + tx;
                val[nt] = (iy >= 0 && iy < 7 && ix >= 0 && ix < 7);
                bofs[nt] = ((size_t)nn[nt] * 49 + iy * 7 + ix) * 2048;
            }
            for (int cis = 0; cis < 64; ++cis) {
                const int kq = cis * 32 + lg * 8;
                bf16x8 a[4];
#pragma unroll
                for (int mt = 0; mt < 4; ++mt)
                    a[mt] = *(const bf16x8*)(wAf +
                            ((size_t)((tap * 16 + wave * 4 + mt) * 64 + cis) * 64 + lane) * 8);
                bf16x8 b[4];
#pragma unroll
                for (int nt = 0; nt < 4; ++nt)
                    b[nt] = val[nt] ? *(const bf16x8*)(flatT + bofs[nt] + kq) : zfrag;
#pragma unroll
                for (int nt = 0; nt < 4; ++nt)
#pragma unroll
                    for (int mt = 0; mt < 4; ++mt)
                        acc[mt][nt] = __builtin_amdgcn_mfma_f32_16x16x32_bf16(a[mt], b[nt], acc[mt][nt], 0, 0, 0);
            }
        }
#pragma unroll
        for (int mt = 0; mt < 4; ++mt)
#pragma unroll
            for (int nt = 0; nt < 4; ++nt) {
                int co0 = wave * 64 + mt * 16 + lg * 4;
                ushort_t v[4];
#pragma unroll
                for (int r = 0; r < 4; ++r)
                    v[r] = f2bf(fmaxf(acc[mt][nt][r] + m1_b[co0 + r], 0.f));
                uint2 u;
                u.x = (uint32)v[0] | ((uint32)v[1] << 16);
                u.y = (uint32)v[2] | ((uint32)v[3] << 16);
                *(uint2*)(m1outT + (size_t)colv[nt] * 256 + co0) = u;
            }
        return;
    }
    // ---- fc1: LDS-staged W, counted-vmcnt software pipeline.
    const int h = bid - 77;
    const int x = h & 7, t = h >> 3;
    const int colTile = t >> 2, rem = t & 3;
    const int kc = x * 2 + (rem & 1), br = rem >> 1;
    const float* W = br ? Wb : Wc;
    const int ncol0 = colTile * 128 + wave * 32;
    const float* wbase = W + (size_t)(kc * 6272) * 4096 + colTile * 128;
    const int srow = lane >> 5, scol = (lane & 31) * 4;

    auto stage = [&](int buf, int s) {
        const float* g0 = wbase + ((size_t)(s * 32 + wave * 8 + srow)) * 4096 + scol;
#pragma unroll
        for (int q = 0; q < 4; ++q) {
            const float* g = g0 + (size_t)(q * 2) * 4096;
            float* l = &wlds[buf][wave * 8 + q * 2][0];
            __builtin_amdgcn_global_load_lds((glob_uint*)g, (lds_uint*)l, 16, 0, 0);
        }
    };

    f32x4 acc0[7], acc1[7];
#pragma unroll
    for (int tt = 0; tt < 7; ++tt) { acc0[tt] = zz; acc1[tt] = zz; }

    const ushort_t* ap = flatA + ((size_t)(kc * 196) * 112 + l15) * 32 + lg * 8;
    stage(0, 0);
    bf16x8 afc[7];
#pragma unroll
    for (int tt = 0; tt < 7; ++tt) afc[tt] = *(const bf16x8*)(ap + (size_t)tt * 512);
    asm volatile("s_waitcnt vmcnt(0)" ::: "memory");
    __builtin_amdgcn_sched_barrier(0);
    __builtin_amdgcn_s_barrier();
    __builtin_amdgcn_sched_barrier(0);

    for (int s = 0; s < 196; ++s) {
        const int b = s & 1;
        bf16x8 afn[7];
        if (s + 1 < 196) {
            const ushort_t* apn = ap + 3584;
#pragma unroll
            for (int tt = 0; tt < 7; ++tt) afn[tt] = *(const bf16x8*)(apn + (size_t)tt * 512);
            stage(b ^ 1, s + 1);
            asm volatile("s_waitcnt vmcnt(11)" ::: "memory");   // af(s)+stage(s) done; 11 newest fly on
        } else {
#pragma unroll
            for (int tt = 0; tt < 7; ++tt) afn[tt] = afc[tt];   // keep defined
            asm volatile("s_waitcnt vmcnt(0)" ::: "memory");
        }
        __builtin_amdgcn_sched_barrier(0);
        __builtin_amdgcn_s_barrier();            // A: all waves' stage(s) visible
        __builtin_amdgcn_sched_barrier(0);
        const float* wrow = &wlds[b][lg * 8][wave * 32 + l15];
        BWU b0u, b1u;
#pragma unroll
        for (int i = 0; i < 4; ++i) {
            float w0a = wrow[(2 * i) * 128], w0b = wrow[(2 * i + 1) * 128];
            float w1a = wrow[(2 * i) * 128 + 16], w1b = wrow[(2 * i + 1) * 128 + 16];
            asm("v_cvt_pk_bf16_f32 %0, %1, %2" : "=v"(b0u.u[i]) : "v"(w0a), "v"(w0b));
            asm("v_cvt_pk_bf16_f32 %0, %1, %2" : "=v"(b1u.u[i]) : "v"(w1a), "v"(w1b));
        }
#pragma unroll
        for (int tt = 0; tt < 7; ++tt) {
            acc0[tt] = __builtin_amdgcn_mfma_f32_16x16x32_bf16(afc[tt], b0u.v8, acc0[tt], 0, 0, 0);
            acc1[tt] = __builtin_amdgcn_mfma_f32_16x16x32_bf16(afc[tt], b1u.v8, acc1[tt], 0, 0, 0);
        }
        __builtin_amdgcn_sched_barrier(0);
        __builtin_amdgcn_s_barrier();            // B: buf b reads done before next stage hits it
        __builtin_amdgcn_sched_barrier(0);
#pragma unroll
        for (int tt = 0; tt < 7; ++tt) afc[tt] = afn[tt];
        ap += 3584;
    }
    float* pb = part + (size_t)(br * 16 + kc) * 112 * 4096;
#pragma unroll
    for (int tt = 0; tt < 7; ++tt)
#pragma unroll
        for (int r = 0; r < 4; ++r) {
            int m = tt * 16 + lg * 4 + r;
            pb[(size_t)m * 4096 + ncol0 + l15] = acc0[tt][r];
            pb[(size_t)m * 4096 + ncol0 + 16 + l15] = acc1[tt][r];
        }
}

// ---------------------------------------------------------------- fused fc1-reduce + fc2 heads (2 k-halves x 8 accs)
__global__ __launch_bounds__(256) void k_fc2(const float* __restrict__ part,
                                             const float* __restrict__ fc1c_b,
                                             const float* __restrict__ fc1b_b,
                                             const float* __restrict__ Wc,
                                             const float* __restrict__ bc,
                                             const float* __restrict__ Wb,
                                             const float* __restrict__ bb,
                                             float* __restrict__ out) {
    __shared__ float h_s[2][4096];
    __shared__ float ph[2][91];
    __shared__ float pbx[2][4];
    const int m = blockIdx.x, tid = threadIdx.x;
    for (int i = tid; i < 8192; i += 256) {
        int br = i >> 12, col = i & 4095;
        float s = br ? fc1b_b[col] : fc1c_b[col];
#pragma unroll
        for (int p = 0; p < 16; ++p) s += part[((size_t)(br * 16 + p) * 112 + m) * 4096 + col];
        h_s[br][col] = fmaxf(s, 0.f);
    }
    __syncthreads();
    const int half = tid >> 7, col = tid & 127;
    if (col < 91) {
        const float* hrow = &h_s[0][half * 2048];
        const float* wp = Wc + (size_t)half * 2048 * 91 + col;
        float a0 = 0, a1 = 0, a2 = 0, a3 = 0, a4 = 0, a5 = 0, a6 = 0, a7 = 0;
        for (int k = 0; k < 2048; k += 8) {
            a0 = fmaf(hrow[k],     wp[(size_t)k * 91], a0);
            a1 = fmaf(hrow[k + 1], wp[(size_t)(k + 1) * 91], a1);
            a2 = fmaf(hrow[k + 2], wp[(size_t)(k + 2) * 91], a2);
            a3 = fmaf(hrow[k + 3], wp[(size_t)(k + 3) * 91], a3);
            a4 = fmaf(hrow[k + 4], wp[(size_t)(k + 4) * 91], a4);
            a5 = fmaf(hrow[k + 5], wp[(size_t)(k + 5) * 91], a5);
            a6 = fmaf(hrow[k + 6], wp[(size_t)(k + 6) * 91], a6);
            a7 = fmaf(hrow[k + 7], wp[(size_t)(k + 7) * 91], a7);
        }
        ph[half][col] = ((a0 + a1) + (a2 + a3)) + ((a4 + a5) + (a6 + a7));
    } else if (col >= 96 && col < 100) {
        int bcol = col - 96;
        const float* hrow = &h_s[1][half * 2048];
        const float* wp = Wb + (size_t)half * 2048 * 4 + bcol;
        float a0 = 0, a1 = 0, a2 = 0, a3 = 0, a4 = 0, a5 = 0, a6 = 0, a7 = 0;
        for (int k = 0; k < 2048; k += 8) {
            a0 = fmaf(hrow[k],     wp[(size_t)k * 4], a0);
            a1 = fmaf(hrow[k + 1], wp[(size_t)(k + 1) * 4], a1);
            a2 = fmaf(hrow[k + 2], wp[(size_t)(k + 2) * 4], a2);
            a3 = fmaf(hrow[k + 3], wp[(size_t)(k + 3) * 4], a3);
            a4 = fmaf(hrow[k + 4], wp[(size_t)(k + 4) * 4], a4);
            a5 = fmaf(hrow[k + 5], wp[(size_t)(k + 5) * 4], a5);
            a6 = fmaf(hrow[k + 6], wp[(size_t)(k + 6) * 4], a6);
            a7 = fmaf(hrow[k + 7], wp[(size_t)(k + 7) * 4], a7);
        }
        pbx[half][bcol] = ((a0 + a1) + (a2 + a3)) + ((a4 + a5) + (a6 + a7));
    }
    __syncthreads();
    if (tid < 91) out[m * 91 + tid] = bc[tid] + ph[0][tid] + ph[1][tid];
    else if (tid >= 96 && tid < 100) {
        int bcol = tid - 96;
        out[9100 + m * 4 + bcol] = bb[bcol] + pbx[0][bcol] + pbx[1][bcol];
    }
}

// ---------------------------------------------------------------- transposed conv 2x2 s2 as GEMM
__global__ __launch_bounds__(256) void k_up(const ushort_t* __restrict__ m1outT,
                                            const ushort_t* __restrict__ wA2f,
                                            ushort_t* __restrict__ upT) {
    const int nb = blockIdx.x, cq = blockIdx.y, tid = threadIdx.x;
    const int wave = tid >> 6, lane = tid & 63, l15 = lane & 15, lg = lane >> 4;
    int colv[4];
#pragma unroll
    for (int nt = 0; nt < 4; ++nt) colv[nt] = nb * 64 + nt * 16 + l15;
    f32x4 acc[4][4];
    const f32x4 zz = {0.f, 0.f, 0.f, 0.f};
#pragma unroll
    for (int a = 0; a < 4; ++a)
#pragma unroll
        for (int b = 0; b < 4; ++b) acc[a][b] = zz;
    for (int cis = 0; cis < 8; ++cis) {
        const int kq = cis * 32 + lg * 8;
        bf16x8 a[4];
#pragma unroll
        for (int mt = 0; mt < 4; ++mt)
            a[mt] = *(const bf16x8*)(wA2f +
                    ((size_t)((cq * 16 + wave * 4 + mt) * 8 + cis) * 64 + lane) * 8);
        bf16x8 b[4];
#pragma unroll
        for (int nt = 0; nt < 4; ++nt)
            b[nt] = *(const bf16x8*)(m1outT + (size_t)colv[nt] * 256 + kq);
#pragma unroll
        for (int nt = 0; nt < 4; ++nt)
#pragma unroll
            for (int mt = 0; mt < 4; ++mt)
                acc[mt][nt] = __builtin_amdgcn_mfma_f32_16x16x32_bf16(a[mt], b[nt], acc[mt][nt], 0, 0, 0);
    }
#pragma unroll
    for (int mt = 0; mt < 4; ++mt)
#pragma unroll
        for (int nt = 0; nt < 4; ++nt) {
            int rb = (cq * 16 + wave * 4 + mt) * 16 + lg * 4;
            ushort_t v[4];
#pragma unroll
            for (int r = 0; r < 4; ++r) v[r] = f2bf(acc[mt][nt][r]);
            uint2 u;
            u.x = (uint32)v[0] | ((uint32)v[1] << 16);
            u.y = (uint32)v[2] | ((uint32)v[3] << 16);
            *(uint2*)(upT + (size_t)colv[nt] * 1024 + rb) = u;
        }
}

// ---------------------------------------------------------------- final mask 1x1 conv (+bias/relu of up)
__global__ void k_mask(const ushort_t* __restrict__ upT, const float* __restrict__ mt_b,
                       const float* __restrict__ m2_w, const float* __restrict__ m2_b,
                       float* __restrict__ out) {
    const int n = blockIdx.x, t = threadIdx.x;
    if (t >= 196) return;
    const int ys = t / 14, xs = t % 14;
    const int ro = (ys & 1) * 2 + (xs & 1);
    const int col = n * 49 + (ys >> 1) * 7 + (xs >> 1);
    const ushort_t* up0 = upT + (size_t)col * 1024 + ro;
    float a0 = m2_b[0], a1 = 0.f, a2 = 0.f, a3 = 0.f;
#pragma unroll 4
    for (int o = 0; o < 256; o += 4) {
        a0 = fmaf(m2_w[o],     fmaxf(bf2f(up0[(o) * 4]) + mt_b[o], 0.f), a0);
        a1 = fmaf(m2_w[o + 1], fmaxf(bf2f(up0[(o + 1) * 4]) + mt_b[o + 1], 0.f), a1);
        a2 = fmaf(m2_w[o + 2], fmaxf(bf2f(up0[(o + 2) * 4]) + mt_b[o + 2], 0.f), a2);
        a3 = fmaf(m2_w[o + 3], fmaxf(bf2f(up0[(o + 3) * 4]) + mt_b[o + 3], 0.f), a3);
    }
    out[9500 + n * 196 + t] = (a0 + a1) + (a2 + a3);
}

// ================================================================ launch
extern "C" void kernel_launch(void* const* d_in, const int* in_sizes, int n_in,
                              void* d_out, int out_size, void* d_ws, size_t ws_size,
                              hipStream_t stream) {
    const float* x      = (const float*)d_in[0];
    const float* rpn_w  = (const float*)d_in[1];
    const float* rpn_b  = (const float*)d_in[2];
    const float* cls_w  = (const float*)d_in[3];
    const float* cls_b  = (const float*)d_in[4];
    const float* bbox_w = (const float*)d_in[5];
    const float* bbox_b = (const float*)d_in[6];
    const float* fc1c_w = (const float*)d_in[7];
    const float* fc1c_b = (const float*)d_in[8];
    const float* fc2c_w = (const float*)d_in[9];
    const float* fc2c_b = (const float*)d_in[10];
    const float* fc1b_w = (const float*)d_in[11];
    const float* fc1b_b = (const float*)d_in[12];
    const float* fc2b_w = (const float*)d_in[13];
    const float* fc2b_b = (const float*)d_in[14];
    const float* m1_w   = (const float*)d_in[15];
    const float* m1_b   = (const float*)d_in[16];
    const float* mt_w   = (const float*)d_in[17];
    const float* mt_b   = (const float*)d_in[18];
    const float* m2_w   = (const float*)d_in[19];
    const float* m2_b   = (const float*)d_in[20];
    float* out = (float*)d_out;

    char* ws = (char*)d_ws;
    size_t off = 0;
    auto take = [&](size_t nbytes) -> char* {
        char* p = ws + off;
        off += (nbytes + 255) & ~(size_t)255;
        return p;
    };
    float* xt      = (float*)take(2097152);                 // 256 x 2048 f32
    float* fpart   = (float*)take(4194304);                 // 8 x 512 x 256 f32
    float* f       = (float*)take(524288);                  // 512 x 256 f32
    float* scores  = (float*)take(9216);
    float* boxes   = (float*)take(36864);
    float* ssort   = (float*)take(9216);
    float* bsort   = (float*)take(36864);
    unsigned long long* adj = (unsigned long long*)take(663552);  // 2304 x 36 u64
    float* fb      = (float*)take(1600);                    // 100 x 4 f32
    ushort_t* flatA = (ushort_t*)take(22478848);            // 3136 x 112 x 32 bf16
    ushort_t* flatT = (ushort_t*)take(20471808);            // 102 x 49 x 2048 bf16
    float* part1   = (float*)take(58720256);                // 2 x 16 x 112 x 4096 f32
    ushort_t* wAf  = (ushort_t*)take(9437184);              // 9x16x64x64x8 bf16
    ushort_t* m1outT = (ushort_t*)take(2523136);            // 4928 x 256 bf16
    ushort_t* wA2f = (ushort_t*)take(524288);               // 64x8x64x8 bf16
    ushort_t* upT  = (ushort_t*)part1;                      // reuse (part1 dead after k_fc2)

    k_pre<<<2560, 256, 0, stream>>>(x, rpn_w, fpart, m1_w, mt_w, wAf, wA2f, xt);
    k_rpn_reduce<<<512, 256, 0, stream>>>(fpart, rpn_b, f);
    k_head<<<9, 256, 0, stream>>>(f, cls_w, cls_b, bbox_w, bbox_b, scores, boxes);
    k_sort<<<9, 256, 0, stream>>>(scores, boxes, ssort, bsort);
    k_adj<<<2304, 64, 0, stream>>>(bsort, adj);
    k_nms<<<1, 64, 0, stream>>>(adj, bsort, fb);
    k_roi<<<dim3(8, 100), 256, 0, stream>>>(xt, fb, flatA, flatT);
    k_big<<<1101, 256, 0, stream>>>(flatA, flatT, fc1c_w, fc1b_w, part1, wAf, m1_b, m1outT);
    k_fc2<<<100, 256, 0, stream>>>(part1, fc1c_b, fc1b_b, fc2c_w, fc2c_b, fc2b_w, fc2b_b, out);
    k_up<<<dim3(77, 4), 256, 0, stream>>>(m1outT, wA2f, upT);
    k_mask<<<100, 256, 0, stream>>>(upT, mt_b, m2_w, m2_b, out);
}